// Round 1
// baseline (1651.076 us; speedup 1.0000x reference)
//
#include <hip/hip_runtime.h>
#include <stdint.h>

#define LT 256
#define LI 2048
#define LL 2304
#define DD 2048
#define NH 16
#define HD 128
#define MLPD 8192
#define EPSF 1e-6f

typedef __attribute__((ext_vector_type(8))) short short8;
typedef __attribute__((ext_vector_type(4))) float floatx4;

__device__ __forceinline__ unsigned short f2bf(float f){
  unsigned u = __float_as_uint(f);
  u += 0x7fff + ((u >> 16) & 1u);
  return (unsigned short)(u >> 16);
}
__device__ __forceinline__ float bf2f(unsigned short h){
  return __uint_as_float(((unsigned)h) << 16);
}

// ---------------------------------------------------------------- mod init
__global__ __launch_bounds__(256) void k_mod_init(float* __restrict__ mod,
                                                  const float* __restrict__ bi,
                                                  const float* __restrict__ bt){
  int i = blockIdx.x * 256 + threadIdx.x;
  if (i < 12288) mod[i] = bi[i];
  else           mod[i] = bt[i - 12288];
}

// silu(vec) @ mod_w, split-K atomics. grid (48 colblk, 4 kchunk, 2 stream)
__global__ __launch_bounds__(256) void k_mod_gemv(const float* __restrict__ vec,
                                                  const float* __restrict__ wi,
                                                  const float* __restrict__ wt,
                                                  float* __restrict__ mod){
  __shared__ float sv[512];
  int str = blockIdx.z;
  int k0 = blockIdx.y * 512;
  int n  = blockIdx.x * 256 + threadIdx.x;
  for (int j = threadIdx.x; j < 512; j += 256){
    float v = vec[k0 + j];
    sv[j] = v / (1.f + expf(-v));
  }
  __syncthreads();
  const float* W = str ? wt : wi;
  float acc = 0.f;
  #pragma unroll 8
  for (int k = 0; k < 512; k++) acc += sv[k] * W[(size_t)(k0 + k) * 12288 + n];
  atomicAdd(&mod[str * 12288 + n], acc);
}

// ------------------------------------------- weight transpose fp32 -> bf16 T
// src (K,N) fp32 row-major -> dst (N,K) bf16 row-major
__global__ __launch_bounds__(256) void k_transpose_w(const float* __restrict__ src,
                                                     unsigned short* __restrict__ dst,
                                                     int K, int N){
  __shared__ float t[32][33];
  int n0 = blockIdx.x * 32, k0 = blockIdx.y * 32;
  int tx = threadIdx.x & 31, ty = threadIdx.x >> 5;
  #pragma unroll
  for (int r = ty; r < 32; r += 8) t[r][tx] = src[(size_t)(k0 + r) * N + n0 + tx];
  __syncthreads();
  #pragma unroll
  for (int r = ty; r < 32; r += 8) dst[(size_t)(n0 + r) * K + k0 + tx] = f2bf(t[tx][r]);
}

// v_arr[h][l][d] -> vt[h][d][l]  (bf16)
__global__ __launch_bounds__(256) void k_transpose_v(const unsigned short* __restrict__ src,
                                                     unsigned short* __restrict__ dst){
  __shared__ unsigned short t[32][33];
  int h = blockIdx.z;
  int d0 = blockIdx.x * 32, l0 = blockIdx.y * 32;
  int tx = threadIdx.x & 31, ty = threadIdx.x >> 5;
  #pragma unroll
  for (int r = ty; r < 32; r += 8) t[r][tx] = src[((size_t)h * LL + l0 + r) * HD + d0 + tx];
  __syncthreads();
  #pragma unroll
  for (int r = ty; r < 32; r += 8) dst[((size_t)h * HD + d0 + r) * LL + l0 + tx] = t[tx][r];
}

// ---------------------------------------------------- LayerNorm + modulate
__global__ __launch_bounds__(256) void k_ln_mod(const float* __restrict__ x,
                                                unsigned short* __restrict__ y,
                                                const float* __restrict__ sh,
                                                const float* __restrict__ sc){
  int row = blockIdx.x;
  const float* xr = x + (size_t)row * DD;
  float v[8];
  float s = 0.f, s2 = 0.f;
  #pragma unroll
  for (int j = 0; j < 8; j++){
    float t = xr[threadIdx.x + j * 256];
    v[j] = t; s += t; s2 += t * t;
  }
  #pragma unroll
  for (int off = 32; off > 0; off >>= 1){ s += __shfl_xor(s, off); s2 += __shfl_xor(s2, off); }
  __shared__ float red[8];
  int wave = threadIdx.x >> 6;
  if ((threadIdx.x & 63) == 0){ red[wave * 2] = s; red[wave * 2 + 1] = s2; }
  __syncthreads();
  float ts  = red[0] + red[2] + red[4] + red[6];
  float ts2 = red[1] + red[3] + red[5] + red[7];
  float mu  = ts * (1.f / 2048.f);
  float var = ts2 * (1.f / 2048.f) - mu * mu;
  float rsn = rsqrtf(var + EPSF);
  #pragma unroll
  for (int j = 0; j < 8; j++){
    int c = threadIdx.x + j * 256;
    y[(size_t)row * DD + c] = f2bf((v[j] - mu) * rsn * (1.f + sc[c]) + sh[c]);
  }
}

// ------------------------------------------ qkv postprocess: rmsnorm + rope
__global__ __launch_bounds__(64) void k_qkv_post(const float* __restrict__ qkv_t,
                                                 const float* __restrict__ qkv_i,
                                                 const float* __restrict__ qs_t,
                                                 const float* __restrict__ ks_t,
                                                 const float* __restrict__ qs_i,
                                                 const float* __restrict__ ks_i,
                                                 const float* __restrict__ pe,
                                                 unsigned short* __restrict__ qa,
                                                 unsigned short* __restrict__ ka,
                                                 unsigned short* __restrict__ va){
  int l = blockIdx.x, h = blockIdx.y;
  const float* src; const float* qsc; const float* ksc;
  if (l < LT){ src = qkv_t + (size_t)l * 3 * DD; qsc = qs_t; ksc = ks_t; }
  else       { src = qkv_i + (size_t)(l - LT) * 3 * DD; qsc = qs_i; ksc = ks_i; }
  int t = threadIdx.x;
  int d0 = 2 * t;
  float q0 = src[h * HD + d0],          q1 = src[h * HD + d0 + 1];
  float k0 = src[DD + h * HD + d0],     k1 = src[DD + h * HD + d0 + 1];
  float v0 = src[2 * DD + h * HD + d0], v1 = src[2 * DD + h * HD + d0 + 1];
  float sq = q0 * q0 + q1 * q1, sk = k0 * k0 + k1 * k1;
  #pragma unroll
  for (int off = 32; off > 0; off >>= 1){ sq += __shfl_xor(sq, off); sk += __shfl_xor(sk, off); }
  float rq = rsqrtf(sq * (1.f / 128.f) + EPSF);
  float rk = rsqrtf(sk * (1.f / 128.f) + EPSF);
  float qn0 = q0 * rq * qsc[d0], qn1 = q1 * rq * qsc[d0 + 1];
  float kn0 = k0 * rk * ksc[d0], kn1 = k1 * rk * ksc[d0 + 1];
  const float* p = pe + (size_t)l * 256 + t * 4;
  float p00 = p[0], p01 = p[1], p10 = p[2], p11 = p[3];
  float qr0 = p00 * qn0 + p01 * qn1, qr1 = p10 * qn0 + p11 * qn1;
  float kr0 = p00 * kn0 + p01 * kn1, kr1 = p10 * kn0 + p11 * kn1;
  const float qsl = 0.08838834764831845f;  // 1/sqrt(128)
  size_t idx = ((size_t)h * LL + l) * HD + d0;
  qa[idx] = f2bf(qr0 * qsl); qa[idx + 1] = f2bf(qr1 * qsl);
  ka[idx] = f2bf(kr0);       ka[idx + 1] = f2bf(kr1);
  va[idx] = f2bf(v0);        va[idx + 1] = f2bf(v1);
}

// --------------------------------------------------------------- MFMA GEMM
// C[M,N] = A[M,K](bf16) @ BT[N,K](bf16)^T  with fused epilogues
#define GM_NONE 0
#define GM_GELU 1
#define GM_RES  2

template<int MODE>
__global__ __launch_bounds__(256) void k_gemm(const unsigned short* __restrict__ A,
                                              const unsigned short* __restrict__ BT,
                                              void* __restrict__ OUT,
                                              const float* __restrict__ bias,
                                              const float* __restrict__ gate,
                                              const float* __restrict__ res,
                                              int M, int N, int K){
  __shared__ __align__(16) unsigned short As[128 * 72];
  __shared__ __align__(16) unsigned short Bs[128 * 72];
  int tid = threadIdx.x;
  int wave = tid >> 6, lane = tid & 63, ln = lane & 15, q4 = lane >> 4;
  int wm = wave & 1, wn = wave >> 1;
  int m0 = blockIdx.y * 128, n0 = blockIdx.x * 128;
  floatx4 acc[4][4];
  #pragma unroll
  for (int i = 0; i < 4; i++)
    #pragma unroll
    for (int j = 0; j < 4; j++) acc[i][j] = (floatx4){0.f, 0.f, 0.f, 0.f};
  for (int k0 = 0; k0 < K; k0 += 64){
    __syncthreads();
    #pragma unroll
    for (int i = 0; i < 4; i++){
      int slot = tid + i * 256;
      int row = slot >> 3, k8 = slot & 7;
      *(uint4*)&As[row * 72 + k8 * 8] = *(const uint4*)&A [(size_t)(m0 + row) * K + k0 + k8 * 8];
      *(uint4*)&Bs[row * 72 + k8 * 8] = *(const uint4*)&BT[(size_t)(n0 + row) * K + k0 + k8 * 8];
    }
    __syncthreads();
    #pragma unroll
    for (int ks = 0; ks < 2; ks++){
      short8 af[4], bf[4];
      #pragma unroll
      for (int mt = 0; mt < 4; mt++)
        af[mt] = *(const short8*)&As[(wm * 64 + mt * 16 + ln) * 72 + ks * 32 + q4 * 8];
      #pragma unroll
      for (int nt = 0; nt < 4; nt++)
        bf[nt] = *(const short8*)&Bs[(wn * 64 + nt * 16 + ln) * 72 + ks * 32 + q4 * 8];
      #pragma unroll
      for (int mt = 0; mt < 4; mt++)
        #pragma unroll
        for (int nt = 0; nt < 4; nt++)
          acc[mt][nt] = __builtin_amdgcn_mfma_f32_16x16x32_bf16(af[mt], bf[nt], acc[mt][nt], 0, 0, 0);
    }
  }
  #pragma unroll
  for (int mt = 0; mt < 4; mt++){
    #pragma unroll
    for (int nt = 0; nt < 4; nt++){
      #pragma unroll
      for (int i = 0; i < 4; i++){
        int row = m0 + wm * 64 + mt * 16 + q4 * 4 + i;
        int col = n0 + wn * 64 + nt * 16 + ln;
        float v = acc[mt][nt][i];
        size_t oidx = (size_t)row * N + col;
        if (MODE == GM_NONE){
          ((float*)OUT)[oidx] = v;
        } else if (MODE == GM_GELU){
          float x = v + bias[col];
          float g = 0.5f * x * (1.f + tanhf(0.7978845608028654f * (x + 0.044715f * x * x * x)));
          ((unsigned short*)OUT)[oidx] = f2bf(g);
        } else {
          float x = v + bias[col];
          ((float*)OUT)[oidx] = res[oidx] + gate[col] * x;
        }
      }
    }
  }
}

// ------------------------------------------------------------ flash attention
// grid (36 q-tiles, 16 heads), 256 threads; BM=64 (16 rows/wave), BN=64
__global__ __launch_bounds__(256) void k_flash(const unsigned short* __restrict__ qa,
                                               const unsigned short* __restrict__ ka,
                                               const unsigned short* __restrict__ vt,
                                               unsigned short* __restrict__ attn){
  __shared__ __align__(16) unsigned short Ks[64 * 136];
  __shared__ __align__(16) unsigned short Vs[128 * 72];
  __shared__ __align__(16) unsigned short Ps[4 * 16 * 72];
  int tid = threadIdx.x;
  int wave = tid >> 6, lane = tid & 63, ln = lane & 15, q4 = lane >> 4;
  int qt = blockIdx.x, h = blockIdx.y;
  const unsigned short* qrow = qa + ((size_t)h * LL + qt * 64 + wave * 16 + ln) * HD;
  short8 qf[4];
  #pragma unroll
  for (int ks = 0; ks < 4; ks++) qf[ks] = *(const short8*)&qrow[ks * 32 + q4 * 8];
  floatx4 o[8];
  #pragma unroll
  for (int i = 0; i < 8; i++) o[i] = (floatx4){0.f, 0.f, 0.f, 0.f};
  float m_i[4] = {-1e30f, -1e30f, -1e30f, -1e30f};
  float l_i[4] = {0.f, 0.f, 0.f, 0.f};
  for (int kv = 0; kv < LL / 64; kv++){
    __syncthreads();
    #pragma unroll
    for (int i = 0; i < 4; i++){
      int slot = tid + i * 256;
      int key = slot >> 4, d8 = slot & 15;
      *(uint4*)&Ks[key * 136 + d8 * 8] =
          *(const uint4*)&ka[((size_t)h * LL + kv * 64 + key) * HD + d8 * 8];
      int d = slot >> 3, k8 = slot & 7;
      *(uint4*)&Vs[d * 72 + k8 * 8] =
          *(const uint4*)&vt[((size_t)h * HD + d) * LL + kv * 64 + k8 * 8];
    }
    __syncthreads();
    floatx4 s[4];
    #pragma unroll
    for (int nt = 0; nt < 4; nt++){
      s[nt] = (floatx4){0.f, 0.f, 0.f, 0.f};
      #pragma unroll
      for (int ks = 0; ks < 4; ks++){
        short8 bf = *(const short8*)&Ks[(nt * 16 + ln) * 136 + ks * 32 + q4 * 8];
        s[nt] = __builtin_amdgcn_mfma_f32_16x16x32_bf16(qf[ks], bf, s[nt], 0, 0, 0);
      }
    }
    float alpha[4];
    #pragma unroll
    for (int i = 0; i < 4; i++){
      float mx = fmaxf(fmaxf(s[0][i], s[1][i]), fmaxf(s[2][i], s[3][i]));
      #pragma unroll
      for (int off = 8; off > 0; off >>= 1) mx = fmaxf(mx, __shfl_xor(mx, off));
      float mnew = fmaxf(m_i[i], mx);
      alpha[i] = expf(m_i[i] - mnew);
      float rs = 0.f;
      #pragma unroll
      for (int nt = 0; nt < 4; nt++){
        float p = expf(s[nt][i] - mnew);
        s[nt][i] = p;
        rs += p;
      }
      #pragma unroll
      for (int off = 8; off > 0; off >>= 1) rs += __shfl_xor(rs, off);
      l_i[i] = alpha[i] * l_i[i] + rs;
      m_i[i] = mnew;
    }
    #pragma unroll
    for (int dt = 0; dt < 8; dt++)
      #pragma unroll
      for (int i = 0; i < 4; i++) o[dt][i] *= alpha[i];
    unsigned short* Pw = &Ps[wave * 16 * 72];
    #pragma unroll
    for (int nt = 0; nt < 4; nt++)
      #pragma unroll
      for (int i = 0; i < 4; i++)
        Pw[(q4 * 4 + i) * 72 + nt * 16 + ln] = f2bf(s[nt][i]);
    short8 af0 = *(const short8*)&Pw[ln * 72 + q4 * 8];
    short8 af1 = *(const short8*)&Pw[ln * 72 + 32 + q4 * 8];
    #pragma unroll
    for (int dt = 0; dt < 8; dt++){
      short8 vf0 = *(const short8*)&Vs[(dt * 16 + ln) * 72 + q4 * 8];
      short8 vf1 = *(const short8*)&Vs[(dt * 16 + ln) * 72 + 32 + q4 * 8];
      o[dt] = __builtin_amdgcn_mfma_f32_16x16x32_bf16(af0, vf0, o[dt], 0, 0, 0);
      o[dt] = __builtin_amdgcn_mfma_f32_16x16x32_bf16(af1, vf1, o[dt], 0, 0, 0);
    }
  }
  #pragma unroll
  for (int i = 0; i < 4; i++) l_i[i] = 1.f / l_i[i];
  int rbase = qt * 64 + wave * 16 + q4 * 4;
  #pragma unroll
  for (int dt = 0; dt < 8; dt++)
    #pragma unroll
    for (int i = 0; i < 4; i++)
      attn[(size_t)(rbase + i) * DD + h * HD + dt * 16 + ln] = f2bf(o[dt][i] * l_i[i]);
}

// ---------------------------------------------------------------- host side
extern "C" void kernel_launch(void* const* d_in, const int* in_sizes, int n_in,
                              void* d_out, int out_size, void* d_ws, size_t ws_size,
                              hipStream_t stream){
  (void)in_sizes; (void)n_in; (void)out_size; (void)ws_size;
  const float* img     = (const float*)d_in[0];
  const float* txt     = (const float*)d_in[1];
  const float* vec     = (const float*)d_in[2];
  const float* pe      = (const float*)d_in[3];
  const float* i_mod_w = (const float*)d_in[4];
  const float* i_mod_b = (const float*)d_in[5];
  const float* i_qkv_w = (const float*)d_in[6];
  const float* i_qs    = (const float*)d_in[7];
  const float* i_ks    = (const float*)d_in[8];
  const float* i_projw = (const float*)d_in[9];
  const float* i_projb = (const float*)d_in[10];
  const float* i_w1    = (const float*)d_in[11];
  const float* i_b1    = (const float*)d_in[12];
  const float* i_w2    = (const float*)d_in[13];
  const float* i_b2    = (const float*)d_in[14];
  const float* t_mod_w = (const float*)d_in[15];
  const float* t_mod_b = (const float*)d_in[16];
  const float* t_qkv_w = (const float*)d_in[17];
  const float* t_qs    = (const float*)d_in[18];
  const float* t_ks    = (const float*)d_in[19];
  const float* t_projw = (const float*)d_in[20];
  const float* t_projb = (const float*)d_in[21];
  const float* t_w1    = (const float*)d_in[22];
  const float* t_b1    = (const float*)d_in[23];
  const float* t_w2    = (const float*)d_in[24];
  const float* t_b2    = (const float*)d_in[25];

  char* ws = (char*)d_ws;
  size_t off = 0;
  auto alloc = [&](size_t b){ size_t r = off; off += (b + 255) & ~(size_t)255; return r; };
  unsigned short* wt_qkv_i  = (unsigned short*)(ws + alloc((size_t)6144 * 2048 * 2));
  unsigned short* wt_qkv_t  = (unsigned short*)(ws + alloc((size_t)6144 * 2048 * 2));
  unsigned short* wt_proj_i = (unsigned short*)(ws + alloc((size_t)2048 * 2048 * 2));
  unsigned short* wt_proj_t = (unsigned short*)(ws + alloc((size_t)2048 * 2048 * 2));
  unsigned short* wt_w1_i   = (unsigned short*)(ws + alloc((size_t)8192 * 2048 * 2));
  unsigned short* wt_w1_t   = (unsigned short*)(ws + alloc((size_t)8192 * 2048 * 2));
  unsigned short* wt_w2_i   = (unsigned short*)(ws + alloc((size_t)2048 * 8192 * 2));
  unsigned short* wt_w2_t   = (unsigned short*)(ws + alloc((size_t)2048 * 8192 * 2));
  float*          mod       = (float*)(ws + alloc((size_t)2 * 12288 * 4));
  unsigned short* xmod_i    = (unsigned short*)(ws + alloc((size_t)LI * DD * 2));
  unsigned short* xmod_t    = (unsigned short*)(ws + alloc((size_t)LT * DD * 2));
  float*          qkv_i     = (float*)(ws + alloc((size_t)LI * 3 * DD * 4));
  float*          qkv_t     = (float*)(ws + alloc((size_t)LT * 3 * DD * 4));
  unsigned short* qarr      = (unsigned short*)(ws + alloc((size_t)NH * LL * HD * 2));
  unsigned short* karr      = (unsigned short*)(ws + alloc((size_t)NH * LL * HD * 2));
  unsigned short* varr      = (unsigned short*)(ws + alloc((size_t)NH * LL * HD * 2));
  unsigned short* vtr       = (unsigned short*)(ws + alloc((size_t)NH * LL * HD * 2));
  unsigned short* attn      = (unsigned short*)(ws + alloc((size_t)LL * DD * 2));
  unsigned short* xmod2_i   = (unsigned short*)(ws + alloc((size_t)LI * DD * 2));
  unsigned short* xmod2_t   = (unsigned short*)(ws + alloc((size_t)LT * DD * 2));
  unsigned short* mlph_i    = (unsigned short*)(ws + alloc((size_t)LI * MLPD * 2));
  unsigned short* mlph_t    = (unsigned short*)(ws + alloc((size_t)LT * MLPD * 2));

  float* out_img = (float*)d_out;
  float* out_txt = out_img + (size_t)LI * DD;

  // 1. modulation vectors
  k_mod_init<<<96, 256, 0, stream>>>(mod, i_mod_b, t_mod_b);
  k_mod_gemv<<<dim3(48, 4, 2), 256, 0, stream>>>(vec, i_mod_w, t_mod_w, mod);

  // 2. weight transposes (fp32 -> bf16, N x K)
  k_transpose_w<<<dim3(192, 64),  256, 0, stream>>>(i_qkv_w, wt_qkv_i, 2048, 6144);
  k_transpose_w<<<dim3(192, 64),  256, 0, stream>>>(t_qkv_w, wt_qkv_t, 2048, 6144);
  k_transpose_w<<<dim3(64, 64),   256, 0, stream>>>(i_projw, wt_proj_i, 2048, 2048);
  k_transpose_w<<<dim3(64, 64),   256, 0, stream>>>(t_projw, wt_proj_t, 2048, 2048);
  k_transpose_w<<<dim3(256, 64),  256, 0, stream>>>(i_w1, wt_w1_i, 2048, 8192);
  k_transpose_w<<<dim3(256, 64),  256, 0, stream>>>(t_w1, wt_w1_t, 2048, 8192);
  k_transpose_w<<<dim3(64, 256),  256, 0, stream>>>(i_w2, wt_w2_i, 8192, 2048);
  k_transpose_w<<<dim3(64, 256),  256, 0, stream>>>(t_w2, wt_w2_t, 8192, 2048);

  // 3. LN + modulate (stage 1)
  k_ln_mod<<<LI, 256, 0, stream>>>(img, xmod_i, mod + 0,     mod + 2048);
  k_ln_mod<<<LT, 256, 0, stream>>>(txt, xmod_t, mod + 12288, mod + 12288 + 2048);

  // 4. qkv GEMMs
  k_gemm<GM_NONE><<<dim3(48, 16), 256, 0, stream>>>(xmod_i, wt_qkv_i, qkv_i,
                                                    nullptr, nullptr, nullptr, LI, 6144, 2048);
  k_gemm<GM_NONE><<<dim3(48, 2),  256, 0, stream>>>(xmod_t, wt_qkv_t, qkv_t,
                                                    nullptr, nullptr, nullptr, LT, 6144, 2048);

  // 5. per-head rmsnorm + rope + concat
  k_qkv_post<<<dim3(LL, NH), 64, 0, stream>>>(qkv_t, qkv_i, t_qs, t_ks, i_qs, i_ks,
                                              pe, qarr, karr, varr);
  k_transpose_v<<<dim3(4, 72, NH), 256, 0, stream>>>(varr, vtr);

  // 6. attention
  k_flash<<<dim3(36, NH), 256, 0, stream>>>(qarr, karr, vtr, attn);

  // 7. proj + gated residual -> d_out
  k_gemm<GM_RES><<<dim3(16, 16), 256, 0, stream>>>(attn + (size_t)LT * DD, wt_proj_i, out_img,
                                                   i_projb, mod + 4096, img, LI, 2048, 2048);
  k_gemm<GM_RES><<<dim3(16, 2),  256, 0, stream>>>(attn, wt_proj_t, out_txt,
                                                   t_projb, mod + 12288 + 4096, txt, LT, 2048, 2048);

  // 8. LN + modulate (stage 2)
  k_ln_mod<<<LI, 256, 0, stream>>>(out_img, xmod2_i, mod + 6144,         mod + 8192);
  k_ln_mod<<<LT, 256, 0, stream>>>(out_txt, xmod2_t, mod + 12288 + 6144, mod + 12288 + 8192);

  // 9. MLP
  k_gemm<GM_GELU><<<dim3(64, 16), 256, 0, stream>>>(xmod2_i, wt_w1_i, mlph_i,
                                                    i_b1, nullptr, nullptr, LI, 8192, 2048);
  k_gemm<GM_GELU><<<dim3(64, 2),  256, 0, stream>>>(xmod2_t, wt_w1_t, mlph_t,
                                                    t_b1, nullptr, nullptr, LT, 8192, 2048);
  k_gemm<GM_RES><<<dim3(16, 16),  256, 0, stream>>>(mlph_i, wt_w2_i, out_img,
                                                    i_b2, mod + 10240, out_img, LI, 2048, 8192);
  k_gemm<GM_RES><<<dim3(16, 2),   256, 0, stream>>>(mlph_t, wt_w2_t, out_txt,
                                                    t_b2, mod + 12288 + 10240, out_txt, LT, 2048, 8192);
}

// Round 2
// 1575.147 us; speedup vs baseline: 1.0482x; 1.0482x over previous
//
#include <hip/hip_runtime.h>
#include <stdint.h>

#define LT 256
#define LI 2048
#define LL 2304
#define DD 2048
#define NH 16
#define HD 128
#define MLPD 8192
#define EPSF 1e-6f

typedef __attribute__((ext_vector_type(8))) short short8;
typedef __attribute__((ext_vector_type(4))) float floatx4;

__device__ __forceinline__ unsigned short f2bf(float f){
  unsigned u = __float_as_uint(f);
  u += 0x7fff + ((u >> 16) & 1u);
  return (unsigned short)(u >> 16);
}
__device__ __forceinline__ unsigned pack_bf2(float a, float b){
  return ((unsigned)f2bf(a)) | (((unsigned)f2bf(b)) << 16);
}
// async 16B global -> LDS (wave-uniform LDS base + lane*16)
__device__ __forceinline__ void gll16(const void* g, void* l){
  __builtin_amdgcn_global_load_lds((const __attribute__((address_space(1))) unsigned int*)g,
                                   (__attribute__((address_space(3))) unsigned int*)l, 16, 0, 0);
}

// ---------------------------------------------------------------- mod init
__global__ __launch_bounds__(256) void k_mod_init(float* __restrict__ mod,
                                                  const float* __restrict__ bi,
                                                  const float* __restrict__ bt){
  int i = blockIdx.x * 256 + threadIdx.x;
  if (i < 12288) mod[i] = bi[i];
  else           mod[i] = bt[i - 12288];
}

__global__ __launch_bounds__(256) void k_mod_gemv(const float* __restrict__ vec,
                                                  const float* __restrict__ wi,
                                                  const float* __restrict__ wt,
                                                  float* __restrict__ mod){
  __shared__ float sv[512];
  int str = blockIdx.z;
  int k0 = blockIdx.y * 512;
  int n  = blockIdx.x * 256 + threadIdx.x;
  for (int j = threadIdx.x; j < 512; j += 256){
    float v = vec[k0 + j];
    sv[j] = v / (1.f + expf(-v));
  }
  __syncthreads();
  const float* W = str ? wt : wi;
  float acc = 0.f;
  #pragma unroll 8
  for (int k = 0; k < 512; k++) acc += sv[k] * W[(size_t)(k0 + k) * 12288 + n];
  atomicAdd(&mod[str * 12288 + n], acc);
}

// ------------------------------------------- weight transpose fp32 -> bf16 T
__global__ __launch_bounds__(256) void k_transpose_w(const float* __restrict__ src,
                                                     unsigned short* __restrict__ dst,
                                                     int K, int N){
  __shared__ float t[32][33];
  int n0 = blockIdx.x * 32, k0 = blockIdx.y * 32;
  int tx = threadIdx.x & 31, ty = threadIdx.x >> 5;
  #pragma unroll
  for (int r = ty; r < 32; r += 8) t[r][tx] = src[(size_t)(k0 + r) * N + n0 + tx];
  __syncthreads();
  #pragma unroll
  for (int r = ty; r < 32; r += 8) dst[(size_t)(n0 + r) * K + k0 + tx] = f2bf(t[tx][r]);
}

// v_arr[h][l][d] -> vt[h][d][l]  (bf16)
__global__ __launch_bounds__(256) void k_transpose_v(const unsigned short* __restrict__ src,
                                                     unsigned short* __restrict__ dst){
  __shared__ unsigned short t[32][33];
  int h = blockIdx.z;
  int d0 = blockIdx.x * 32, l0 = blockIdx.y * 32;
  int tx = threadIdx.x & 31, ty = threadIdx.x >> 5;
  #pragma unroll
  for (int r = ty; r < 32; r += 8) t[r][tx] = src[((size_t)h * LL + l0 + r) * HD + d0 + tx];
  __syncthreads();
  #pragma unroll
  for (int r = ty; r < 32; r += 8) dst[((size_t)h * HD + d0 + r) * LL + l0 + tx] = t[tx][r];
}

// ---------------------------------------------------- LayerNorm + modulate
__global__ __launch_bounds__(256) void k_ln_mod(const float* __restrict__ x,
                                                unsigned short* __restrict__ y,
                                                const float* __restrict__ sh,
                                                const float* __restrict__ sc){
  int row = blockIdx.x;
  const float* xr = x + (size_t)row * DD;
  float v[8];
  float s = 0.f, s2 = 0.f;
  #pragma unroll
  for (int j = 0; j < 8; j++){
    float t = xr[threadIdx.x + j * 256];
    v[j] = t; s += t; s2 += t * t;
  }
  #pragma unroll
  for (int off = 32; off > 0; off >>= 1){ s += __shfl_xor(s, off); s2 += __shfl_xor(s2, off); }
  __shared__ float red[8];
  int wave = threadIdx.x >> 6;
  if ((threadIdx.x & 63) == 0){ red[wave * 2] = s; red[wave * 2 + 1] = s2; }
  __syncthreads();
  float ts  = red[0] + red[2] + red[4] + red[6];
  float ts2 = red[1] + red[3] + red[5] + red[7];
  float mu  = ts * (1.f / 2048.f);
  float var = ts2 * (1.f / 2048.f) - mu * mu;
  float rsn = rsqrtf(var + EPSF);
  #pragma unroll
  for (int j = 0; j < 8; j++){
    int c = threadIdx.x + j * 256;
    y[(size_t)row * DD + c] = f2bf((v[j] - mu) * rsn * (1.f + sc[c]) + sh[c]);
  }
}

// ------------------------------------------ qkv postprocess: rmsnorm + rope
// q additionally scaled by (1/sqrt(128))*log2(e) so attention runs in exp2 domain
__global__ __launch_bounds__(256) void k_qkv_post(const float* __restrict__ qkv_t,
                                                  const float* __restrict__ qkv_i,
                                                  const float* __restrict__ qs_t,
                                                  const float* __restrict__ ks_t,
                                                  const float* __restrict__ qs_i,
                                                  const float* __restrict__ ks_i,
                                                  const float* __restrict__ pe,
                                                  unsigned short* __restrict__ qa,
                                                  unsigned short* __restrict__ ka,
                                                  unsigned short* __restrict__ va){
  int wave = threadIdx.x >> 6, t = threadIdx.x & 63;
  int l = blockIdx.x * 4 + wave, h = blockIdx.y;
  const float* src; const float* qsc; const float* ksc;
  if (l < LT){ src = qkv_t + (size_t)l * 3 * DD; qsc = qs_t; ksc = ks_t; }
  else       { src = qkv_i + (size_t)(l - LT) * 3 * DD; qsc = qs_i; ksc = ks_i; }
  int d0 = 2 * t;
  float q0 = src[h * HD + d0],          q1 = src[h * HD + d0 + 1];
  float k0 = src[DD + h * HD + d0],     k1 = src[DD + h * HD + d0 + 1];
  float v0 = src[2 * DD + h * HD + d0], v1 = src[2 * DD + h * HD + d0 + 1];
  float sq = q0 * q0 + q1 * q1, sk = k0 * k0 + k1 * k1;
  #pragma unroll
  for (int off = 32; off > 0; off >>= 1){ sq += __shfl_xor(sq, off); sk += __shfl_xor(sk, off); }
  float rq = rsqrtf(sq * (1.f / 128.f) + EPSF);
  float rk = rsqrtf(sk * (1.f / 128.f) + EPSF);
  float qn0 = q0 * rq * qsc[d0], qn1 = q1 * rq * qsc[d0 + 1];
  float kn0 = k0 * rk * ksc[d0], kn1 = k1 * rk * ksc[d0 + 1];
  const float* p = pe + (size_t)l * 256 + t * 4;
  float p00 = p[0], p01 = p[1], p10 = p[2], p11 = p[3];
  float qr0 = p00 * qn0 + p01 * qn1, qr1 = p10 * qn0 + p11 * qn1;
  float kr0 = p00 * kn0 + p01 * kn1, kr1 = p10 * kn0 + p11 * kn1;
  const float qsl = 0.08838834764831845f * 1.4426950408889634f;
  size_t idx = ((size_t)h * LL + l) * HD + d0;
  qa[idx] = f2bf(qr0 * qsl); qa[idx + 1] = f2bf(qr1 * qsl);
  ka[idx] = f2bf(kr0);       ka[idx + 1] = f2bf(kr1);
  va[idx] = f2bf(v0);        va[idx + 1] = f2bf(v1);
}

// --------------------------------------------------------------- MFMA GEMM
// C[M,N] = A[M,K](bf16) @ BT[N,K](bf16)^T, m97 structure: global_load_lds
// width-16 + XOR-swizzled LDS (swizzle folded into the GLOBAL address).
#define GM_NONE 0
#define GM_GELU 1
#define GM_RES  2

template<int MODE>
__global__ __launch_bounds__(256) void k_gemm(const unsigned short* __restrict__ A,
                                              const unsigned short* __restrict__ BT,
                                              void* __restrict__ OUT,
                                              const float* __restrict__ bias,
                                              const float* __restrict__ gate,
                                              const float* __restrict__ res,
                                              int M, int N, int K){
  __shared__ __align__(16) unsigned short As[128 * 64];
  __shared__ __align__(16) unsigned short Bs[128 * 64];
  int tid = threadIdx.x;
  int wave = tid >> 6, lane = tid & 63, ln = lane & 15, q4 = lane >> 4;
  int wm = wave & 1, wn = wave >> 1;
  int l7 = ln & 7;
  int m0 = blockIdx.y * 128, n0 = blockIdx.x * 128;
  int srow[4], scol[4], sbase[4];
  #pragma unroll
  for (int t = 0; t < 4; t++){
    int idx = t * 256 + wave * 64 + lane;
    srow[t]  = idx >> 3;
    scol[t]  = ((idx & 7) ^ (srow[t] & 7)) << 3;
    sbase[t] = (t * 256 + wave * 64) * 8;
  }
  floatx4 acc[4][4];
  #pragma unroll
  for (int i = 0; i < 4; i++)
    #pragma unroll
    for (int j = 0; j < 4; j++) acc[i][j] = (floatx4){0.f, 0.f, 0.f, 0.f};
  for (int k0 = 0; k0 < K; k0 += 64){
    __syncthreads();
    #pragma unroll
    for (int t = 0; t < 4; t++)
      gll16(&A[(size_t)(m0 + srow[t]) * K + k0 + scol[t]], &As[sbase[t]]);
    #pragma unroll
    for (int t = 0; t < 4; t++)
      gll16(&BT[(size_t)(n0 + srow[t]) * K + k0 + scol[t]], &Bs[sbase[t]]);
    __syncthreads();
    #pragma unroll
    for (int ks = 0; ks < 2; ks++){
      int uoff = ((ks * 4 + q4) ^ l7) << 3;
      short8 af[4], bf[4];
      #pragma unroll
      for (int mt = 0; mt < 4; mt++)
        af[mt] = *(const short8*)&As[((wm * 64 + mt * 16 + ln) << 6) + uoff];
      #pragma unroll
      for (int nt = 0; nt < 4; nt++)
        bf[nt] = *(const short8*)&Bs[((wn * 64 + nt * 16 + ln) << 6) + uoff];
      #pragma unroll
      for (int mt = 0; mt < 4; mt++)
        #pragma unroll
        for (int nt = 0; nt < 4; nt++)
          acc[mt][nt] = __builtin_amdgcn_mfma_f32_16x16x32_bf16(af[mt], bf[nt], acc[mt][nt], 0, 0, 0);
    }
  }
  #pragma unroll
  for (int mt = 0; mt < 4; mt++){
    #pragma unroll
    for (int nt = 0; nt < 4; nt++){
      #pragma unroll
      for (int i = 0; i < 4; i++){
        int row = m0 + wm * 64 + mt * 16 + q4 * 4 + i;
        int col = n0 + wn * 64 + nt * 16 + ln;
        float v = acc[mt][nt][i];
        size_t oidx = (size_t)row * N + col;
        if (MODE == GM_NONE){
          ((float*)OUT)[oidx] = v;
        } else if (MODE == GM_GELU){
          float x = v + bias[col];
          float z = 2.3022104f * (x + 0.044715f * x * x * x);  // 2*0.79788456*log2e
          float g = x / (1.f + exp2f(-z));
          ((unsigned short*)OUT)[oidx] = f2bf(g);
        } else {
          float x = v + bias[col];
          ((float*)OUT)[oidx] = res[oidx] + gate[col] * x;
        }
      }
    }
  }
}

// ------------------------------------------------------------ flash attention
// S^T = K·Q^T (C row = key, col = q)  ->  O^T = V^T·P^T.
// Block: 4 waves x 32 q-rows = 128 q-rows; KV split in 2 halves across blocks.
// Scores arrive pre-scaled by log2(e): softmax uses exp2.
__global__ __launch_bounds__(256) void k_flash(const unsigned short* __restrict__ qa,
                                               const unsigned short* __restrict__ ka,
                                               const unsigned short* __restrict__ vt,
                                               float* __restrict__ opart,
                                               float* __restrict__ mlpart){
  __shared__ __align__(16) unsigned short Ks[64 * 128];   // [key][d] swizzled
  __shared__ __align__(16) unsigned short Vs[128 * 64];   // [d][key] swizzled
  __shared__ __align__(16) unsigned short Ps[4 * 32 * 72];// per-wave P[q][key], pad 72
  int tid = threadIdx.x;
  int wave = tid >> 6, lane = tid & 63, ln = lane & 15, q4 = lane >> 4;
  int l7 = ln & 7;
  int qt = blockIdx.x, half = blockIdx.y, h = blockIdx.z;
  int qbase = qt * 128 + wave * 32;
  int kv0 = half * 1152;

  // Q fragments (B-operand: lane ln holds row q, k-contig)
  short8 qf[2][4];
  #pragma unroll
  for (int qt2 = 0; qt2 < 2; qt2++)
    #pragma unroll
    for (int ks = 0; ks < 4; ks++)
      qf[qt2][ks] = *(const short8*)&qa[((size_t)h * LL + qbase + qt2 * 16 + ln) * HD + ks * 32 + q4 * 8];

  floatx4 o[8][2];
  #pragma unroll
  for (int dt = 0; dt < 8; dt++){ o[dt][0] = (floatx4){0,0,0,0}; o[dt][1] = (floatx4){0,0,0,0}; }
  float m_i[2] = {-1e30f, -1e30f};
  float l_i[2] = {0.f, 0.f};
  unsigned short* Pw = &Ps[wave * 32 * 72];

  int srowK[4], scolK[4], srowV[4], scolV[4], sbase[4];
  #pragma unroll
  for (int t = 0; t < 4; t++){
    int idx = t * 256 + wave * 64 + lane;
    srowK[t] = idx >> 4; scolK[t] = ((idx & 15) ^ (srowK[t] & 7)) << 3;
    srowV[t] = idx >> 3; scolV[t] = ((idx & 7)  ^ (srowV[t] & 7)) << 3;
    sbase[t] = (t * 256 + wave * 64) * 8;
  }

  for (int it = 0; it < 18; it++){
    int kvb = kv0 + it * 64;
    __syncthreads();
    #pragma unroll
    for (int t = 0; t < 4; t++)
      gll16(&ka[((size_t)h * LL + kvb + srowK[t]) * HD + scolK[t]], &Ks[sbase[t]]);
    #pragma unroll
    for (int t = 0; t < 4; t++)
      gll16(&vt[((size_t)h * HD + srowV[t]) * LL + kvb + scolV[t]], &Vs[sbase[t]]);
    __syncthreads();

    // S^T = K . Q^T
    floatx4 st[4][2];
    #pragma unroll
    for (int kt = 0; kt < 4; kt++){ st[kt][0] = (floatx4){0,0,0,0}; st[kt][1] = (floatx4){0,0,0,0}; }
    #pragma unroll
    for (int kt = 0; kt < 4; kt++){
      #pragma unroll
      for (int ks = 0; ks < 4; ks++){
        short8 kf = *(const short8*)&Ks[((kt * 16 + ln) << 7) + ((((ks * 4 + q4) ^ l7)) << 3)];
        st[kt][0] = __builtin_amdgcn_mfma_f32_16x16x32_bf16(kf, qf[0][ks], st[kt][0], 0, 0, 0);
        st[kt][1] = __builtin_amdgcn_mfma_f32_16x16x32_bf16(kf, qf[1][ks], st[kt][1], 0, 0, 0);
      }
    }

    // online softmax per q column (col = qt2*16+ln)
    float alpha[2];
    #pragma unroll
    for (int qt2 = 0; qt2 < 2; qt2++){
      float mx = -1e30f;
      #pragma unroll
      for (int kt = 0; kt < 4; kt++)
        #pragma unroll
        for (int i = 0; i < 4; i++) mx = fmaxf(mx, st[kt][qt2][i]);
      mx = fmaxf(mx, __shfl_xor(mx, 16));
      mx = fmaxf(mx, __shfl_xor(mx, 32));
      float mnew = fmaxf(m_i[qt2], mx);
      alpha[qt2] = exp2f(m_i[qt2] - mnew);
      float rs = 0.f;
      #pragma unroll
      for (int kt = 0; kt < 4; kt++)
        #pragma unroll
        for (int i = 0; i < 4; i++){
          float p = exp2f(st[kt][qt2][i] - mnew);
          st[kt][qt2][i] = p; rs += p;
        }
      rs += __shfl_xor(rs, 16);
      rs += __shfl_xor(rs, 32);
      l_i[qt2] = alpha[qt2] * l_i[qt2] + rs;
      m_i[qt2] = mnew;
    }
    #pragma unroll
    for (int dt = 0; dt < 8; dt++)
      #pragma unroll
      for (int qt2 = 0; qt2 < 2; qt2++)
        #pragma unroll
        for (int i = 0; i < 4; i++) o[dt][qt2][i] *= alpha[qt2];

    // P[q][key] (b64 packed writes), then read back as PV B-operand
    #pragma unroll
    for (int kt = 0; kt < 4; kt++)
      #pragma unroll
      for (int qt2 = 0; qt2 < 2; qt2++){
        uint2 pk;
        pk.x = pack_bf2(st[kt][qt2][0], st[kt][qt2][1]);
        pk.y = pack_bf2(st[kt][qt2][2], st[kt][qt2][3]);
        *(uint2*)&Pw[(qt2 * 16 + ln) * 72 + kt * 16 + q4 * 4] = pk;
      }
    short8 pf[2][2];
    #pragma unroll
    for (int qt2 = 0; qt2 < 2; qt2++)
      #pragma unroll
      for (int kc = 0; kc < 2; kc++)
        pf[qt2][kc] = *(const short8*)&Pw[(qt2 * 16 + ln) * 72 + kc * 32 + q4 * 8];

    // O^T += V^T . P^T
    #pragma unroll
    for (int dt = 0; dt < 8; dt++){
      #pragma unroll
      for (int kc = 0; kc < 2; kc++){
        short8 vf = *(const short8*)&Vs[((dt * 16 + ln) << 6) + ((((kc * 4 + q4) ^ l7)) << 3)];
        o[dt][0] = __builtin_amdgcn_mfma_f32_16x16x32_bf16(vf, pf[0][kc], o[dt][0], 0, 0, 0);
        o[dt][1] = __builtin_amdgcn_mfma_f32_16x16x32_bf16(vf, pf[1][kc], o[dt][1], 0, 0, 0);
      }
    }
  }

  // store raw partial O + (m,l)
  #pragma unroll
  for (int qt2 = 0; qt2 < 2; qt2++){
    int qg = qbase + qt2 * 16 + ln;
    size_t base = (((size_t)half * NH + h) * LL + qg) * HD;
    #pragma unroll
    for (int dt = 0; dt < 8; dt++){
      float4 v; v.x = o[dt][qt2][0]; v.y = o[dt][qt2][1]; v.z = o[dt][qt2][2]; v.w = o[dt][qt2][3];
      *(float4*)&opart[base + dt * 16 + q4 * 4] = v;
    }
    if (q4 == 0){
      size_t mb = (((size_t)half * NH + h) * LL + qg) * 2;
      mlpart[mb] = m_i[qt2]; mlpart[mb + 1] = l_i[qt2];
    }
  }
}

// combine the two KV halves -> attn[q][h*128+d] bf16
__global__ __launch_bounds__(256) void k_comb(const float* __restrict__ opart,
                                              const float* __restrict__ mlpart,
                                              unsigned short* __restrict__ attn){
  int idx = blockIdx.x * 256 + threadIdx.x;  // 16*2304*32
  int d4 = idx & 31;
  int q  = (idx >> 5) % LL;
  int h  = (idx >> 5) / LL;
  size_t mb0 = (((size_t)0 * NH + h) * LL + q) * 2;
  size_t mb1 = (((size_t)1 * NH + h) * LL + q) * 2;
  float m0 = mlpart[mb0], l0 = mlpart[mb0 + 1];
  float m1 = mlpart[mb1], l1 = mlpart[mb1 + 1];
  float mm = fmaxf(m0, m1);
  float w0 = exp2f(m0 - mm), w1 = exp2f(m1 - mm);
  float dn = 1.f / (w0 * l0 + w1 * l1);
  float4 o0 = *(const float4*)&opart[(((size_t)0 * NH + h) * LL + q) * HD + d4 * 4];
  float4 o1 = *(const float4*)&opart[(((size_t)1 * NH + h) * LL + q) * HD + d4 * 4];
  uint2 pk;
  pk.x = pack_bf2((w0 * o0.x + w1 * o1.x) * dn, (w0 * o0.y + w1 * o1.y) * dn);
  pk.y = pack_bf2((w0 * o0.z + w1 * o1.z) * dn, (w0 * o0.w + w1 * o1.w) * dn);
  *(uint2*)&attn[(size_t)q * DD + h * HD + d4 * 4] = pk;
}

// ---------------------------------------------------------------- host side
extern "C" void kernel_launch(void* const* d_in, const int* in_sizes, int n_in,
                              void* d_out, int out_size, void* d_ws, size_t ws_size,
                              hipStream_t stream){
  (void)in_sizes; (void)n_in; (void)out_size; (void)ws_size;
  const float* img     = (const float*)d_in[0];
  const float* txt     = (const float*)d_in[1];
  const float* vec     = (const float*)d_in[2];
  const float* pe      = (const float*)d_in[3];
  const float* i_mod_w = (const float*)d_in[4];
  const float* i_mod_b = (const float*)d_in[5];
  const float* i_qkv_w = (const float*)d_in[6];
  const float* i_qs    = (const float*)d_in[7];
  const float* i_ks    = (const float*)d_in[8];
  const float* i_projw = (const float*)d_in[9];
  const float* i_projb = (const float*)d_in[10];
  const float* i_w1    = (const float*)d_in[11];
  const float* i_b1    = (const float*)d_in[12];
  const float* i_w2    = (const float*)d_in[13];
  const float* i_b2    = (const float*)d_in[14];
  const float* t_mod_w = (const float*)d_in[15];
  const float* t_mod_b = (const float*)d_in[16];
  const float* t_qkv_w = (const float*)d_in[17];
  const float* t_qs    = (const float*)d_in[18];
  const float* t_ks    = (const float*)d_in[19];
  const float* t_projw = (const float*)d_in[20];
  const float* t_projb = (const float*)d_in[21];
  const float* t_w1    = (const float*)d_in[22];
  const float* t_b1    = (const float*)d_in[23];
  const float* t_w2    = (const float*)d_in[24];
  const float* t_b2    = (const float*)d_in[25];

  char* ws = (char*)d_ws;
  size_t off = 0;
  auto alloc = [&](size_t b){ size_t r = off; off += (b + 255) & ~(size_t)255; return r; };
  unsigned short* wt_qkv_i  = (unsigned short*)(ws + alloc((size_t)6144 * 2048 * 2));
  unsigned short* wt_qkv_t  = (unsigned short*)(ws + alloc((size_t)6144 * 2048 * 2));
  unsigned short* wt_proj_i = (unsigned short*)(ws + alloc((size_t)2048 * 2048 * 2));
  unsigned short* wt_proj_t = (unsigned short*)(ws + alloc((size_t)2048 * 2048 * 2));
  unsigned short* wt_w1_i   = (unsigned short*)(ws + alloc((size_t)8192 * 2048 * 2));
  unsigned short* wt_w1_t   = (unsigned short*)(ws + alloc((size_t)8192 * 2048 * 2));
  unsigned short* wt_w2_i   = (unsigned short*)(ws + alloc((size_t)2048 * 8192 * 2));
  unsigned short* wt_w2_t   = (unsigned short*)(ws + alloc((size_t)2048 * 8192 * 2));
  float*          mod       = (float*)(ws + alloc((size_t)2 * 12288 * 4));
  unsigned short* xmod_i    = (unsigned short*)(ws + alloc((size_t)LI * DD * 2));
  unsigned short* xmod_t    = (unsigned short*)(ws + alloc((size_t)LT * DD * 2));
  float*          qkv_i     = (float*)(ws + alloc((size_t)LI * 3 * DD * 4));
  float*          qkv_t     = (float*)(ws + alloc((size_t)LT * 3 * DD * 4));
  unsigned short* qarr      = (unsigned short*)(ws + alloc((size_t)NH * LL * HD * 2));
  unsigned short* karr      = (unsigned short*)(ws + alloc((size_t)NH * LL * HD * 2));
  unsigned short* varr      = (unsigned short*)(ws + alloc((size_t)NH * LL * HD * 2));
  unsigned short* vtr       = (unsigned short*)(ws + alloc((size_t)NH * LL * HD * 2));
  unsigned short* attn      = (unsigned short*)(ws + alloc((size_t)LL * DD * 2));
  unsigned short* xmod2_i   = (unsigned short*)(ws + alloc((size_t)LI * DD * 2));
  unsigned short* xmod2_t   = (unsigned short*)(ws + alloc((size_t)LT * DD * 2));
  unsigned short* mlph_i    = (unsigned short*)(ws + alloc((size_t)LI * MLPD * 2));
  unsigned short* mlph_t    = (unsigned short*)(ws + alloc((size_t)LT * MLPD * 2));
  // flash partials alias the (dead-after-qkv_post) qkv_i buffer: 38.3MB < 50.3MB
  float* opart  = qkv_i;
  float* mlpart = qkv_i + (size_t)2 * NH * LL * HD;

  float* out_img = (float*)d_out;
  float* out_txt = out_img + (size_t)LI * DD;

  k_mod_init<<<96, 256, 0, stream>>>(mod, i_mod_b, t_mod_b);
  k_mod_gemv<<<dim3(48, 4, 2), 256, 0, stream>>>(vec, i_mod_w, t_mod_w, mod);

  k_transpose_w<<<dim3(192, 64),  256, 0, stream>>>(i_qkv_w, wt_qkv_i, 2048, 6144);
  k_transpose_w<<<dim3(192, 64),  256, 0, stream>>>(t_qkv_w, wt_qkv_t, 2048, 6144);
  k_transpose_w<<<dim3(64, 64),   256, 0, stream>>>(i_projw, wt_proj_i, 2048, 2048);
  k_transpose_w<<<dim3(64, 64),   256, 0, stream>>>(t_projw, wt_proj_t, 2048, 2048);
  k_transpose_w<<<dim3(256, 64),  256, 0, stream>>>(i_w1, wt_w1_i, 2048, 8192);
  k_transpose_w<<<dim3(256, 64),  256, 0, stream>>>(t_w1, wt_w1_t, 2048, 8192);
  k_transpose_w<<<dim3(64, 256),  256, 0, stream>>>(i_w2, wt_w2_i, 8192, 2048);
  k_transpose_w<<<dim3(64, 256),  256, 0, stream>>>(t_w2, wt_w2_t, 8192, 2048);

  k_ln_mod<<<LI, 256, 0, stream>>>(img, xmod_i, mod + 0,     mod + 2048);
  k_ln_mod<<<LT, 256, 0, stream>>>(txt, xmod_t, mod + 12288, mod + 12288 + 2048);

  k_gemm<GM_NONE><<<dim3(48, 16), 256, 0, stream>>>(xmod_i, wt_qkv_i, qkv_i,
                                                    nullptr, nullptr, nullptr, LI, 6144, 2048);
  k_gemm<GM_NONE><<<dim3(48, 2),  256, 0, stream>>>(xmod_t, wt_qkv_t, qkv_t,
                                                    nullptr, nullptr, nullptr, LT, 6144, 2048);

  k_qkv_post<<<dim3(LL / 4, NH), 256, 0, stream>>>(qkv_t, qkv_i, t_qs, t_ks, i_qs, i_ks,
                                                   pe, qarr, karr, varr);
  k_transpose_v<<<dim3(4, 72, NH), 256, 0, stream>>>(varr, vtr);

  k_flash<<<dim3(18, 2, NH), 256, 0, stream>>>(qarr, karr, vtr, opart, mlpart);
  k_comb<<<NH * LL * 32 / 256, 256, 0, stream>>>(opart, mlpart, attn);

  k_gemm<GM_RES><<<dim3(16, 16), 256, 0, stream>>>(attn + (size_t)LT * DD, wt_proj_i, out_img,
                                                   i_projb, mod + 4096, img, LI, 2048, 2048);
  k_gemm<GM_RES><<<dim3(16, 2),  256, 0, stream>>>(attn, wt_proj_t, out_txt,
                                                   t_projb, mod + 12288 + 4096, txt, LT, 2048, 2048);

  k_ln_mod<<<LI, 256, 0, stream>>>(out_img, xmod2_i, mod + 6144,         mod + 8192);
  k_ln_mod<<<LT, 256, 0, stream>>>(out_txt, xmod2_t, mod + 12288 + 6144, mod + 12288 + 8192);

  k_gemm<GM_GELU><<<dim3(64, 16), 256, 0, stream>>>(xmod2_i, wt_w1_i, mlph_i,
                                                    i_b1, nullptr, nullptr, LI, 8192, 2048);
  k_gemm<GM_GELU><<<dim3(64, 2),  256, 0, stream>>>(xmod2_t, wt_w1_t, mlph_t,
                                                    t_b1, nullptr, nullptr, LT, 8192, 2048);
  k_gemm<GM_RES><<<dim3(16, 16),  256, 0, stream>>>(mlph_i, wt_w2_i, out_img,
                                                    i_b2, mod + 10240, out_img, LI, 2048, 8192);
  k_gemm<GM_RES><<<dim3(16, 2),   256, 0, stream>>>(mlph_t, wt_w2_t, out_txt,
                                                    t_b2, mod + 12288 + 10240, out_txt, LT, 2048, 8192);
}

// Round 3
// 1256.463 us; speedup vs baseline: 1.3141x; 1.2536x over previous
//
#include <hip/hip_runtime.h>
#include <stdint.h>

#define LT 256
#define LI 2048
#define LL 2304
#define DD 2048
#define NH 16
#define HD 128
#define MLPD 8192
#define EPSF 1e-6f

typedef __attribute__((ext_vector_type(8))) short short8;
typedef __attribute__((ext_vector_type(4))) float floatx4;

__device__ __forceinline__ unsigned short f2bf(float f){
  unsigned u = __float_as_uint(f);
  u += 0x7fff + ((u >> 16) & 1u);
  return (unsigned short)(u >> 16);
}
__device__ __forceinline__ unsigned pack_bf2(float a, float b){
  return ((unsigned)f2bf(a)) | (((unsigned)f2bf(b)) << 16);
}
// async 16B global -> LDS (wave-uniform LDS base + lane*16)
__device__ __forceinline__ void gll16(const void* g, void* l){
  __builtin_amdgcn_global_load_lds((const __attribute__((address_space(1))) unsigned int*)g,
                                   (__attribute__((address_space(3))) unsigned int*)l, 16, 0, 0);
}

// ---------------------------------------------------------------- mod init
__global__ __launch_bounds__(256) void k_mod_init(float* __restrict__ mod,
                                                  const float* __restrict__ bi,
                                                  const float* __restrict__ bt){
  int i = blockIdx.x * 256 + threadIdx.x;
  if (i < 12288) mod[i] = bi[i];
  else           mod[i] = bt[i - 12288];
}

__global__ __launch_bounds__(256) void k_mod_gemv(const float* __restrict__ vec,
                                                  const float* __restrict__ wi,
                                                  const float* __restrict__ wt,
                                                  float* __restrict__ mod){
  __shared__ float sv[512];
  int str = blockIdx.z;
  int k0 = blockIdx.y * 512;
  int n  = blockIdx.x * 256 + threadIdx.x;
  for (int j = threadIdx.x; j < 512; j += 256){
    float v = vec[k0 + j];
    sv[j] = v / (1.f + expf(-v));
  }
  __syncthreads();
  const float* W = str ? wt : wi;
  float acc = 0.f;
  #pragma unroll 8
  for (int k = 0; k < 512; k++) acc += sv[k] * W[(size_t)(k0 + k) * 12288 + n];
  atomicAdd(&mod[str * 12288 + n], acc);
}

// ------------------------------------------- weight transpose fp32 -> bf16 T
__global__ __launch_bounds__(256) void k_transpose_w(const float* __restrict__ src,
                                                     unsigned short* __restrict__ dst,
                                                     int K, int N){
  __shared__ float t[32][33];
  int n0 = blockIdx.x * 32, k0 = blockIdx.y * 32;
  int tx = threadIdx.x & 31, ty = threadIdx.x >> 5;
  #pragma unroll
  for (int r = ty; r < 32; r += 8) t[r][tx] = src[(size_t)(k0 + r) * N + n0 + tx];
  __syncthreads();
  #pragma unroll
  for (int r = ty; r < 32; r += 8) dst[(size_t)(n0 + r) * K + k0 + tx] = f2bf(t[tx][r]);
}

// v_arr[h][l][d] -> vt[h][d][l]  (bf16)
__global__ __launch_bounds__(256) void k_transpose_v(const unsigned short* __restrict__ src,
                                                     unsigned short* __restrict__ dst){
  __shared__ unsigned short t[32][33];
  int h = blockIdx.z;
  int d0 = blockIdx.x * 32, l0 = blockIdx.y * 32;
  int tx = threadIdx.x & 31, ty = threadIdx.x >> 5;
  #pragma unroll
  for (int r = ty; r < 32; r += 8) t[r][tx] = src[((size_t)h * LL + l0 + r) * HD + d0 + tx];
  __syncthreads();
  #pragma unroll
  for (int r = ty; r < 32; r += 8) dst[((size_t)h * HD + d0 + r) * LL + l0 + tx] = t[tx][r];
}

// ---------------------------------------------------- LayerNorm + modulate
__global__ __launch_bounds__(256) void k_ln_mod(const float* __restrict__ x,
                                                unsigned short* __restrict__ y,
                                                const float* __restrict__ sh,
                                                const float* __restrict__ sc){
  int row = blockIdx.x;
  const float* xr = x + (size_t)row * DD;
  float v[8];
  float s = 0.f, s2 = 0.f;
  #pragma unroll
  for (int j = 0; j < 8; j++){
    float t = xr[threadIdx.x + j * 256];
    v[j] = t; s += t; s2 += t * t;
  }
  #pragma unroll
  for (int off = 32; off > 0; off >>= 1){ s += __shfl_xor(s, off); s2 += __shfl_xor(s2, off); }
  __shared__ float red[8];
  int wave = threadIdx.x >> 6;
  if ((threadIdx.x & 63) == 0){ red[wave * 2] = s; red[wave * 2 + 1] = s2; }
  __syncthreads();
  float ts  = red[0] + red[2] + red[4] + red[6];
  float ts2 = red[1] + red[3] + red[5] + red[7];
  float mu  = ts * (1.f / 2048.f);
  float var = ts2 * (1.f / 2048.f) - mu * mu;
  float rsn = rsqrtf(var + EPSF);
  #pragma unroll
  for (int j = 0; j < 8; j++){
    int c = threadIdx.x + j * 256;
    y[(size_t)row * DD + c] = f2bf((v[j] - mu) * rsn * (1.f + sc[c]) + sh[c]);
  }
}

// ------------------------------------------ qkv postprocess: rmsnorm + rope
__global__ __launch_bounds__(256) void k_qkv_post(const float* __restrict__ qkv_t,
                                                  const float* __restrict__ qkv_i,
                                                  const float* __restrict__ qs_t,
                                                  const float* __restrict__ ks_t,
                                                  const float* __restrict__ qs_i,
                                                  const float* __restrict__ ks_i,
                                                  const float* __restrict__ pe,
                                                  unsigned short* __restrict__ qa,
                                                  unsigned short* __restrict__ ka,
                                                  unsigned short* __restrict__ va){
  int wave = threadIdx.x >> 6, t = threadIdx.x & 63;
  int l = blockIdx.x * 4 + wave, h = blockIdx.y;
  const float* src; const float* qsc; const float* ksc;
  if (l < LT){ src = qkv_t + (size_t)l * 3 * DD; qsc = qs_t; ksc = ks_t; }
  else       { src = qkv_i + (size_t)(l - LT) * 3 * DD; qsc = qs_i; ksc = ks_i; }
  int d0 = 2 * t;
  float q0 = src[h * HD + d0],          q1 = src[h * HD + d0 + 1];
  float k0 = src[DD + h * HD + d0],     k1 = src[DD + h * HD + d0 + 1];
  float v0 = src[2 * DD + h * HD + d0], v1 = src[2 * DD + h * HD + d0 + 1];
  float sq = q0 * q0 + q1 * q1, sk = k0 * k0 + k1 * k1;
  #pragma unroll
  for (int off = 32; off > 0; off >>= 1){ sq += __shfl_xor(sq, off); sk += __shfl_xor(sk, off); }
  float rq = rsqrtf(sq * (1.f / 128.f) + EPSF);
  float rk = rsqrtf(sk * (1.f / 128.f) + EPSF);
  float qn0 = q0 * rq * qsc[d0], qn1 = q1 * rq * qsc[d0 + 1];
  float kn0 = k0 * rk * ksc[d0], kn1 = k1 * rk * ksc[d0 + 1];
  const float* p = pe + (size_t)l * 256 + t * 4;
  float p00 = p[0], p01 = p[1], p10 = p[2], p11 = p[3];
  float qr0 = p00 * qn0 + p01 * qn1, qr1 = p10 * qn0 + p11 * qn1;
  float kr0 = p00 * kn0 + p01 * kn1, kr1 = p10 * kn0 + p11 * kn1;
  const float qsl = 0.08838834764831845f * 1.4426950408889634f;
  size_t idx = ((size_t)h * LL + l) * HD + d0;
  qa[idx] = f2bf(qr0 * qsl); qa[idx + 1] = f2bf(qr1 * qsl);
  ka[idx] = f2bf(kr0);       ka[idx + 1] = f2bf(kr1);
  va[idx] = f2bf(v0);        va[idx + 1] = f2bf(v1);
}

// --------------------------------------------------------------- MFMA GEMM
// Fused 2-problem (img+txt), double-buffered LDS, global_load_lds + XOR swizzle.
#define GM_NONE 0
#define GM_GELU 1
#define GM_RES  2

template<int BM, int MODE>
__global__ __launch_bounds__(256) void k_gemm2(const unsigned short* __restrict__ A0,
                                               const unsigned short* __restrict__ A1,
                                               const unsigned short* __restrict__ B0,
                                               const unsigned short* __restrict__ B1,
                                               void* __restrict__ O0, void* __restrict__ O1,
                                               const float* __restrict__ bias0,
                                               const float* __restrict__ bias1,
                                               const float* __restrict__ gate0,
                                               const float* __restrict__ gate1,
                                               const float* __restrict__ res0,
                                               const float* __restrict__ res1,
                                               int mb0, int N, int K){
  constexpr int MT = BM / 32;          // m-tiles per wave (BM=128 -> 4, BM=64 -> 2)
  constexpr int TA = BM / 32;          // A staging chunks per thread
  __shared__ __align__(16) unsigned short As[2][BM * 64];
  __shared__ __align__(16) unsigned short Bs[2][128 * 64];
  int tid = threadIdx.x;
  int wave = tid >> 6, lane = tid & 63, ln = lane & 15, q4 = lane >> 4;
  int wm = wave & 1, wn = wave >> 1;
  int l7 = ln & 7;

  int yb = blockIdx.y;
  const unsigned short* A; const unsigned short* BT; void* OUT;
  const float* bias; const float* gate; const float* res;
  int m0;
  if (yb < mb0){ A = A0; BT = B0; OUT = O0; bias = bias0; gate = gate0; res = res0; m0 = yb * BM; }
  else         { A = A1; BT = B1; OUT = O1; bias = bias1; gate = gate1; res = res1; m0 = (yb - mb0) * BM; }
  int n0 = blockIdx.x * 128;

  int srA[TA], scA[TA], sbA[TA];
  #pragma unroll
  for (int t = 0; t < TA; t++){
    int idx = t * 256 + tid;
    srA[t] = idx >> 3;
    scA[t] = ((idx & 7) ^ (srA[t] & 7)) << 3;
    sbA[t] = (t * 256 + wave * 64) * 8;
  }
  int srB[4], scB[4], sbB[4];
  #pragma unroll
  for (int t = 0; t < 4; t++){
    int idx = t * 256 + tid;
    srB[t] = idx >> 3;
    scB[t] = ((idx & 7) ^ (srB[t] & 7)) << 3;
    sbB[t] = (t * 256 + wave * 64) * 8;
  }

  auto stage = [&](int buf, int k0){
    #pragma unroll
    for (int t = 0; t < TA; t++)
      gll16(&A[(size_t)(m0 + srA[t]) * K + k0 + scA[t]], &As[buf][sbA[t]]);
    #pragma unroll
    for (int t = 0; t < 4; t++)
      gll16(&BT[(size_t)(n0 + srB[t]) * K + k0 + scB[t]], &Bs[buf][sbB[t]]);
  };

  floatx4 acc[MT][4];
  #pragma unroll
  for (int i = 0; i < MT; i++)
    #pragma unroll
    for (int j = 0; j < 4; j++) acc[i][j] = (floatx4){0.f, 0.f, 0.f, 0.f};

  stage(0, 0);
  int ntiles = K >> 6;
  for (int it = 0; it < ntiles; it++){
    __syncthreads();                       // drains vmcnt: prefetch from last iter
    if (it + 1 < ntiles) stage((it + 1) & 1, (it + 1) << 6);
    int cur = it & 1;
    #pragma unroll
    for (int ks = 0; ks < 2; ks++){
      int uoff = ((ks * 4 + q4) ^ l7) << 3;
      short8 af[MT], bf[4];
      #pragma unroll
      for (int mt = 0; mt < MT; mt++)
        af[mt] = *(const short8*)&As[cur][((wm * (BM / 2) + mt * 16 + ln) << 6) + uoff];
      #pragma unroll
      for (int nt = 0; nt < 4; nt++)
        bf[nt] = *(const short8*)&Bs[cur][((wn * 64 + nt * 16 + ln) << 6) + uoff];
      #pragma unroll
      for (int mt = 0; mt < MT; mt++)
        #pragma unroll
        for (int nt = 0; nt < 4; nt++)
          acc[mt][nt] = __builtin_amdgcn_mfma_f32_16x16x32_bf16(af[mt], bf[nt], acc[mt][nt], 0, 0, 0);
    }
  }

  #pragma unroll
  for (int mt = 0; mt < MT; mt++){
    #pragma unroll
    for (int nt = 0; nt < 4; nt++){
      #pragma unroll
      for (int i = 0; i < 4; i++){
        int row = m0 + wm * (BM / 2) + mt * 16 + q4 * 4 + i;
        int col = n0 + wn * 64 + nt * 16 + ln;
        float v = acc[mt][nt][i];
        size_t oidx = (size_t)row * N + col;
        if (MODE == GM_NONE){
          ((float*)OUT)[oidx] = v;
        } else if (MODE == GM_GELU){
          float x = v + bias[col];
          float z = 2.3022104f * (x + 0.044715f * x * x * x);
          float g = x / (1.f + exp2f(-z));
          ((unsigned short*)OUT)[oidx] = f2bf(g);
        } else {
          float x = v + bias[col];
          ((float*)OUT)[oidx] = res[oidx] + gate[col] * x;
        }
      }
    }
  }
}

// ------------------------------------------------------------ flash attention
__global__ __launch_bounds__(256) void k_flash(const unsigned short* __restrict__ qa,
                                               const unsigned short* __restrict__ ka,
                                               const unsigned short* __restrict__ vt,
                                               float* __restrict__ opart,
                                               float* __restrict__ mlpart){
  __shared__ __align__(16) unsigned short Ks[64 * 128];
  __shared__ __align__(16) unsigned short Vs[128 * 64];
  __shared__ __align__(16) unsigned short Ps[4 * 32 * 72];
  int tid = threadIdx.x;
  int wave = tid >> 6, lane = tid & 63, ln = lane & 15, q4 = lane >> 4;
  int l7 = ln & 7;
  int qt = blockIdx.x, half = blockIdx.y, h = blockIdx.z;
  int qbase = qt * 128 + wave * 32;
  int kv0 = half * 1152;

  short8 qf[2][4];
  #pragma unroll
  for (int qt2 = 0; qt2 < 2; qt2++)
    #pragma unroll
    for (int ks = 0; ks < 4; ks++)
      qf[qt2][ks] = *(const short8*)&qa[((size_t)h * LL + qbase + qt2 * 16 + ln) * HD + ks * 32 + q4 * 8];

  floatx4 o[8][2];
  #pragma unroll
  for (int dt = 0; dt < 8; dt++){ o[dt][0] = (floatx4){0,0,0,0}; o[dt][1] = (floatx4){0,0,0,0}; }
  float m_i[2] = {-1e30f, -1e30f};
  float l_i[2] = {0.f, 0.f};
  unsigned short* Pw = &Ps[wave * 32 * 72];

  int srowK[4], scolK[4], srowV[4], scolV[4], sbase[4];
  #pragma unroll
  for (int t = 0; t < 4; t++){
    int idx = t * 256 + wave * 64 + lane;
    srowK[t] = idx >> 4; scolK[t] = ((idx & 15) ^ (srowK[t] & 7)) << 3;
    srowV[t] = idx >> 3; scolV[t] = ((idx & 7)  ^ (srowV[t] & 7)) << 3;
    sbase[t] = (t * 256 + wave * 64) * 8;
  }

  for (int it = 0; it < 18; it++){
    int kvb = kv0 + it * 64;
    __syncthreads();
    #pragma unroll
    for (int t = 0; t < 4; t++)
      gll16(&ka[((size_t)h * LL + kvb + srowK[t]) * HD + scolK[t]], &Ks[sbase[t]]);
    #pragma unroll
    for (int t = 0; t < 4; t++)
      gll16(&vt[((size_t)h * HD + srowV[t]) * LL + kvb + scolV[t]], &Vs[sbase[t]]);
    __syncthreads();

    floatx4 st[4][2];
    #pragma unroll
    for (int kt = 0; kt < 4; kt++){ st[kt][0] = (floatx4){0,0,0,0}; st[kt][1] = (floatx4){0,0,0,0}; }
    #pragma unroll
    for (int kt = 0; kt < 4; kt++){
      #pragma unroll
      for (int ks = 0; ks < 4; ks++){
        short8 kf = *(const short8*)&Ks[((kt * 16 + ln) << 7) + ((((ks * 4 + q4) ^ l7)) << 3)];
        st[kt][0] = __builtin_amdgcn_mfma_f32_16x16x32_bf16(kf, qf[0][ks], st[kt][0], 0, 0, 0);
        st[kt][1] = __builtin_amdgcn_mfma_f32_16x16x32_bf16(kf, qf[1][ks], st[kt][1], 0, 0, 0);
      }
    }

    float alpha[2];
    #pragma unroll
    for (int qt2 = 0; qt2 < 2; qt2++){
      float mx = -1e30f;
      #pragma unroll
      for (int kt = 0; kt < 4; kt++)
        #pragma unroll
        for (int i = 0; i < 4; i++) mx = fmaxf(mx, st[kt][qt2][i]);
      mx = fmaxf(mx, __shfl_xor(mx, 16));
      mx = fmaxf(mx, __shfl_xor(mx, 32));
      float mnew = fmaxf(m_i[qt2], mx);
      alpha[qt2] = exp2f(m_i[qt2] - mnew);
      float rs = 0.f;
      #pragma unroll
      for (int kt = 0; kt < 4; kt++)
        #pragma unroll
        for (int i = 0; i < 4; i++){
          float p = exp2f(st[kt][qt2][i] - mnew);
          st[kt][qt2][i] = p; rs += p;
        }
      rs += __shfl_xor(rs, 16);
      rs += __shfl_xor(rs, 32);
      l_i[qt2] = alpha[qt2] * l_i[qt2] + rs;
      m_i[qt2] = mnew;
    }
    #pragma unroll
    for (int dt = 0; dt < 8; dt++)
      #pragma unroll
      for (int qt2 = 0; qt2 < 2; qt2++)
        #pragma unroll
        for (int i = 0; i < 4; i++) o[dt][qt2][i] *= alpha[qt2];

    #pragma unroll
    for (int kt = 0; kt < 4; kt++)
      #pragma unroll
      for (int qt2 = 0; qt2 < 2; qt2++){
        uint2 pk;
        pk.x = pack_bf2(st[kt][qt2][0], st[kt][qt2][1]);
        pk.y = pack_bf2(st[kt][qt2][2], st[kt][qt2][3]);
        *(uint2*)&Pw[(qt2 * 16 + ln) * 72 + kt * 16 + q4 * 4] = pk;
      }
    short8 pf[2][2];
    #pragma unroll
    for (int qt2 = 0; qt2 < 2; qt2++)
      #pragma unroll
      for (int kc = 0; kc < 2; kc++)
        pf[qt2][kc] = *(const short8*)&Pw[(qt2 * 16 + ln) * 72 + kc * 32 + q4 * 8];

    #pragma unroll
    for (int dt = 0; dt < 8; dt++){
      #pragma unroll
      for (int kc = 0; kc < 2; kc++){
        short8 vf = *(const short8*)&Vs[((dt * 16 + ln) << 6) + ((((kc * 4 + q4) ^ l7)) << 3)];
        o[dt][0] = __builtin_amdgcn_mfma_f32_16x16x32_bf16(vf, pf[0][kc], o[dt][0], 0, 0, 0);
        o[dt][1] = __builtin_amdgcn_mfma_f32_16x16x32_bf16(vf, pf[1][kc], o[dt][1], 0, 0, 0);
      }
    }
  }

  #pragma unroll
  for (int qt2 = 0; qt2 < 2; qt2++){
    int qg = qbase + qt2 * 16 + ln;
    size_t base = (((size_t)half * NH + h) * LL + qg) * HD;
    #pragma unroll
    for (int dt = 0; dt < 8; dt++){
      float4 v; v.x = o[dt][qt2][0]; v.y = o[dt][qt2][1]; v.z = o[dt][qt2][2]; v.w = o[dt][qt2][3];
      *(float4*)&opart[base + dt * 16 + q4 * 4] = v;
    }
    if (q4 == 0){
      size_t mb = (((size_t)half * NH + h) * LL + qg) * 2;
      mlpart[mb] = m_i[qt2]; mlpart[mb + 1] = l_i[qt2];
    }
  }
}

__global__ __launch_bounds__(256) void k_comb(const float* __restrict__ opart,
                                              const float* __restrict__ mlpart,
                                              unsigned short* __restrict__ attn){
  int idx = blockIdx.x * 256 + threadIdx.x;
  int d4 = idx & 31;
  int q  = (idx >> 5) % LL;
  int h  = (idx >> 5) / LL;
  size_t mb0 = (((size_t)0 * NH + h) * LL + q) * 2;
  size_t mb1 = (((size_t)1 * NH + h) * LL + q) * 2;
  float m0 = mlpart[mb0], l0 = mlpart[mb0 + 1];
  float m1 = mlpart[mb1], l1 = mlpart[mb1 + 1];
  float mm = fmaxf(m0, m1);
  float w0 = exp2f(m0 - mm), w1 = exp2f(m1 - mm);
  float dn = 1.f / (w0 * l0 + w1 * l1);
  float4 o0 = *(const float4*)&opart[(((size_t)0 * NH + h) * LL + q) * HD + d4 * 4];
  float4 o1 = *(const float4*)&opart[(((size_t)1 * NH + h) * LL + q) * HD + d4 * 4];
  uint2 pk;
  pk.x = pack_bf2((w0 * o0.x + w1 * o1.x) * dn, (w0 * o0.y + w1 * o1.y) * dn);
  pk.y = pack_bf2((w0 * o0.z + w1 * o1.z) * dn, (w0 * o0.w + w1 * o1.w) * dn);
  *(uint2*)&attn[(size_t)q * DD + h * HD + d4 * 4] = pk;
}

// ---------------------------------------------------------------- host side
extern "C" void kernel_launch(void* const* d_in, const int* in_sizes, int n_in,
                              void* d_out, int out_size, void* d_ws, size_t ws_size,
                              hipStream_t stream){
  (void)in_sizes; (void)n_in; (void)out_size; (void)ws_size;
  const float* img     = (const float*)d_in[0];
  const float* txt     = (const float*)d_in[1];
  const float* vec     = (const float*)d_in[2];
  const float* pe      = (const float*)d_in[3];
  const float* i_mod_w = (const float*)d_in[4];
  const float* i_mod_b = (const float*)d_in[5];
  const float* i_qkv_w = (const float*)d_in[6];
  const float* i_qs    = (const float*)d_in[7];
  const float* i_ks    = (const float*)d_in[8];
  const float* i_projw = (const float*)d_in[9];
  const float* i_projb = (const float*)d_in[10];
  const float* i_w1    = (const float*)d_in[11];
  const float* i_b1    = (const float*)d_in[12];
  const float* i_w2    = (const float*)d_in[13];
  const float* i_b2    = (const float*)d_in[14];
  const float* t_mod_w = (const float*)d_in[15];
  const float* t_mod_b = (const float*)d_in[16];
  const float* t_qkv_w = (const float*)d_in[17];
  const float* t_qs    = (const float*)d_in[18];
  const float* t_ks    = (const float*)d_in[19];
  const float* t_projw = (const float*)d_in[20];
  const float* t_projb = (const float*)d_in[21];
  const float* t_w1    = (const float*)d_in[22];
  const float* t_b1    = (const float*)d_in[23];
  const float* t_w2    = (const float*)d_in[24];
  const float* t_b2    = (const float*)d_in[25];

  char* ws = (char*)d_ws;
  size_t off = 0;
  auto alloc = [&](size_t b){ size_t r = off; off += (b + 255) & ~(size_t)255; return r; };
  unsigned short* wt_qkv_i  = (unsigned short*)(ws + alloc((size_t)6144 * 2048 * 2));
  unsigned short* wt_qkv_t  = (unsigned short*)(ws + alloc((size_t)6144 * 2048 * 2));
  unsigned short* wt_proj_i = (unsigned short*)(ws + alloc((size_t)2048 * 2048 * 2));
  unsigned short* wt_proj_t = (unsigned short*)(ws + alloc((size_t)2048 * 2048 * 2));
  unsigned short* wt_w1_i   = (unsigned short*)(ws + alloc((size_t)8192 * 2048 * 2));
  unsigned short* wt_w1_t   = (unsigned short*)(ws + alloc((size_t)8192 * 2048 * 2));
  unsigned short* wt_w2_i   = (unsigned short*)(ws + alloc((size_t)2048 * 8192 * 2));
  unsigned short* wt_w2_t   = (unsigned short*)(ws + alloc((size_t)2048 * 8192 * 2));
  float*          mod       = (float*)(ws + alloc((size_t)2 * 12288 * 4));
  unsigned short* xmod_i    = (unsigned short*)(ws + alloc((size_t)LI * DD * 2));
  unsigned short* xmod_t    = (unsigned short*)(ws + alloc((size_t)LT * DD * 2));
  float*          qkv_i     = (float*)(ws + alloc((size_t)LI * 3 * DD * 4));
  float*          qkv_t     = (float*)(ws + alloc((size_t)LT * 3 * DD * 4));
  unsigned short* qarr      = (unsigned short*)(ws + alloc((size_t)NH * LL * HD * 2));
  unsigned short* karr      = (unsigned short*)(ws + alloc((size_t)NH * LL * HD * 2));
  unsigned short* varr      = (unsigned short*)(ws + alloc((size_t)NH * LL * HD * 2));
  unsigned short* vtr       = (unsigned short*)(ws + alloc((size_t)NH * LL * HD * 2));
  unsigned short* attn      = (unsigned short*)(ws + alloc((size_t)LL * DD * 2));
  unsigned short* xmod2_i   = (unsigned short*)(ws + alloc((size_t)LI * DD * 2));
  unsigned short* xmod2_t   = (unsigned short*)(ws + alloc((size_t)LT * DD * 2));
  unsigned short* mlph_i    = (unsigned short*)(ws + alloc((size_t)LI * MLPD * 2));
  unsigned short* mlph_t    = (unsigned short*)(ws + alloc((size_t)LT * MLPD * 2));
  float* opart  = qkv_i;
  float* mlpart = qkv_i + (size_t)2 * NH * LL * HD;

  float* out_img = (float*)d_out;
  float* out_txt = out_img + (size_t)LI * DD;

  k_mod_init<<<96, 256, 0, stream>>>(mod, i_mod_b, t_mod_b);
  k_mod_gemv<<<dim3(48, 4, 2), 256, 0, stream>>>(vec, i_mod_w, t_mod_w, mod);

  k_transpose_w<<<dim3(192, 64),  256, 0, stream>>>(i_qkv_w, wt_qkv_i, 2048, 6144);
  k_transpose_w<<<dim3(192, 64),  256, 0, stream>>>(t_qkv_w, wt_qkv_t, 2048, 6144);
  k_transpose_w<<<dim3(64, 64),   256, 0, stream>>>(i_projw, wt_proj_i, 2048, 2048);
  k_transpose_w<<<dim3(64, 64),   256, 0, stream>>>(t_projw, wt_proj_t, 2048, 2048);
  k_transpose_w<<<dim3(256, 64),  256, 0, stream>>>(i_w1, wt_w1_i, 2048, 8192);
  k_transpose_w<<<dim3(256, 64),  256, 0, stream>>>(t_w1, wt_w1_t, 2048, 8192);
  k_transpose_w<<<dim3(64, 256),  256, 0, stream>>>(i_w2, wt_w2_i, 8192, 2048);
  k_transpose_w<<<dim3(64, 256),  256, 0, stream>>>(t_w2, wt_w2_t, 8192, 2048);

  k_ln_mod<<<LI, 256, 0, stream>>>(img, xmod_i, mod + 0,     mod + 2048);
  k_ln_mod<<<LT, 256, 0, stream>>>(txt, xmod_t, mod + 12288, mod + 12288 + 2048);

  // qkv: fused img+txt, BM=128 -> grid (48, 16+2)
  k_gemm2<128, GM_NONE><<<dim3(48, 18), 256, 0, stream>>>(
      xmod_i, xmod_t, wt_qkv_i, wt_qkv_t, qkv_i, qkv_t,
      nullptr, nullptr, nullptr, nullptr, nullptr, nullptr, 16, 6144, 2048);

  k_qkv_post<<<dim3(LL / 4, NH), 256, 0, stream>>>(qkv_t, qkv_i, t_qs, t_ks, i_qs, i_ks,
                                                   pe, qarr, karr, varr);
  k_transpose_v<<<dim3(4, 72, NH), 256, 0, stream>>>(varr, vtr);

  k_flash<<<dim3(18, 2, NH), 256, 0, stream>>>(qarr, karr, vtr, opart, mlpart);
  k_comb<<<NH * LL * 32 / 256, 256, 0, stream>>>(opart, mlpart, attn);

  // proj: fused, BM=64 -> grid (16, 32+4)
  k_gemm2<64, GM_RES><<<dim3(16, 36), 256, 0, stream>>>(
      attn + (size_t)LT * DD, attn, wt_proj_i, wt_proj_t, out_img, out_txt,
      i_projb, t_projb, mod + 4096, mod + 12288 + 4096, img, txt, 32, 2048, 2048);

  k_ln_mod<<<LI, 256, 0, stream>>>(out_img, xmod2_i, mod + 6144,         mod + 8192);
  k_ln_mod<<<LT, 256, 0, stream>>>(out_txt, xmod2_t, mod + 12288 + 6144, mod + 12288 + 8192);

  // mlp1: fused, BM=128 -> grid (64, 18)
  k_gemm2<128, GM_GELU><<<dim3(64, 18), 256, 0, stream>>>(
      xmod2_i, xmod2_t, wt_w1_i, wt_w1_t, mlph_i, mlph_t,
      i_b1, t_b1, nullptr, nullptr, nullptr, nullptr, 16, 8192, 2048);

  // mlp2: fused, BM=64 -> grid (16, 36)
  k_gemm2<64, GM_RES><<<dim3(16, 36), 256, 0, stream>>>(
      mlph_i, mlph_t, wt_w2_i, wt_w2_t, out_img, out_txt,
      i_b2, t_b2, mod + 10240, mod + 12288 + 10240, out_img, out_txt, 32, 2048, 8192);
}